// Round 2
// baseline (47.960 us; speedup 1.0000x reference)
//
#include <hip/hip_runtime.h>

// ALS gather-dot: out[b] = dot(user[loc[b,0], :], goods[:, loc[b,1]])
// user: [500000, 128] f32 row-major   -> row gather, contiguous (512 B/row)
// goods: [128, 500000] f32 row-major  -> column gather, stride 2 MB (scattered 4 B)
// location: [16384, 2] int            -> out: [16384] f32
//
// R1: 4 outputs per wave. All 8 scattered goods loads + 4 coalesced float2
// u-loads issued before any reduction -> 4x memory-level parallelism per wave.
// A/B probe: latency-bound (Model B) predicts ~30 us; 128B-granule BW-bound
// (Model A) predicts flat ~47 us.

#define KDIM 128
#define GOODS_NUM 500000
#define OPW 4   // outputs per wave

__global__ __launch_bounds__(256) void als_gather_dot4(
    const float* __restrict__ user,
    const float* __restrict__ goods,
    const int* __restrict__ loc,
    float* __restrict__ out,
    int batch)
{
    const int gtid = blockIdx.x * blockDim.x + threadIdx.x;
    const int wave = gtid >> 6;
    const int lane = threadIdx.x & 63;
    const int base = wave * OPW;
    if (base >= batch) return;

    const int r = lane * 2;   // rows r, r+1 of the goods column / elems of u row

    // ---- issue ALL loads first (independent -> all in flight together) ----
    float2 uv[OPW];
    float g0[OPW], g1[OPW];
    #pragma unroll
    for (int j = 0; j < OPW; ++j) {
        const int b = base + j;                       // batch=16384 divisible by OPW
        const int urow = loc[b * 2 + 0];
        const int gcol = loc[b * 2 + 1];
        uv[j] = *reinterpret_cast<const float2*>(
            user + (size_t)urow * KDIM + (size_t)r);
        g0[j] = goods[(size_t)r       * GOODS_NUM + (size_t)gcol];
        g1[j] = goods[(size_t)(r + 1) * GOODS_NUM + (size_t)gcol];
    }

    // ---- reduce each output ----
    #pragma unroll
    for (int j = 0; j < OPW; ++j) {
        float s = uv[j].x * g0[j] + uv[j].y * g1[j];
        #pragma unroll
        for (int off = 32; off >= 1; off >>= 1)
            s += __shfl_xor(s, off, 64);
        if (lane == 0) out[base + j] = s;
    }
}

extern "C" void kernel_launch(void* const* d_in, const int* in_sizes, int n_in,
                              void* d_out, int out_size, void* d_ws, size_t ws_size,
                              hipStream_t stream)
{
    const float* user  = (const float*)d_in[0];
    const float* goods = (const float*)d_in[1];
    const int*   loc   = (const int*)d_in[2];
    float* out = (float*)d_out;

    const int batch = out_size;                         // 16384
    const int waves = (batch + OPW - 1) / OPW;          // 4096
    const int threads = 256;                            // 4 waves/block
    const int blocks = (waves * 64 + threads - 1) / threads;   // 1024
    als_gather_dot4<<<blocks, threads, 0, stream>>>(user, goods, loc, out, batch);
}